// Round 9
// baseline (81.756 us; speedup 1.0000x reference)
//
#include <hip/hip_runtime.h>
#include <math.h>

#define NF 12
#define NB 4096
#define NR 4096
#define NO 8

typedef float f32x4v __attribute__((ext_vector_type(4)));
typedef short bf16x8 __attribute__((ext_vector_type(8)));
typedef unsigned int uint32x4 __attribute__((ext_vector_type(4)));

// ---- ws layout ----
#define PT2_BYTES (128 * 8 * 512 * 2)      // 1,048,576 : bf16 [kt][j<8][512] fragment-ordered
#define WS_NEED (PT2_BYTES + 2048)
// ---- r2 fallback ws layout ----
#define PT_ELEMS (112 * 4096)

__device__ __forceinline__ float softplus_f(float v) {
    return fmaxf(v, 0.0f) + log1pf(__expf(-fabsf(v)));
}
__device__ __forceinline__ unsigned short f2bf(float f) {
    unsigned u = __float_as_uint(f);
    u += 0x7FFFu + ((u >> 16) & 1u);
    return (unsigned short)(u >> 16);
}
__device__ __forceinline__ unsigned cvt_pk_bf16(float a, float b) {
    unsigned r;
    asm("v_cvt_pk_bf16_f32 %0, %1, %2" : "=v"(r) : "v"(a), "v"(b));
    return r;
}

// split an 8-vector of f32 into hi+lo bf16 fragments (error ~2^-18)
__device__ __forceinline__ void build_split(f32x4v va, f32x4v vb,
                                            bf16x8& ah, bf16x8& al) {
    unsigned h0 = cvt_pk_bf16(va[0], va[1]), h1 = cvt_pk_bf16(va[2], va[3]);
    unsigned h2 = cvt_pk_bf16(vb[0], vb[1]), h3 = cvt_pk_bf16(vb[2], vb[3]);
    f32x4v hia = { __uint_as_float(h0 << 16), __uint_as_float(h0 & 0xFFFF0000u),
                   __uint_as_float(h1 << 16), __uint_as_float(h1 & 0xFFFF0000u) };
    f32x4v hib = { __uint_as_float(h2 << 16), __uint_as_float(h2 & 0xFFFF0000u),
                   __uint_as_float(h3 << 16), __uint_as_float(h3 & 0xFFFF0000u) };
    f32x4v ea = va - hia;
    f32x4v eb = vb - hib;
    unsigned q0 = cvt_pk_bf16(ea[0], ea[1]), q1 = cvt_pk_bf16(ea[2], ea[3]);
    unsigned q2 = cvt_pk_bf16(eb[0], eb[1]), q3 = cvt_pk_bf16(eb[2], eb[3]);
    union { uint32x4 u; bf16x8 v; } A, B;
    A.u = (uint32x4){h0, h1, h2, h3};
    B.u = (uint32x4){q0, q1, q2, q3};
    ah = A.v; al = B.v;
}

// ---------------- prep: PT2 fragment-ordered + out zero ----------------
__global__ __launch_bounds__(512) void anfis_prep4(
    const float* __restrict__ cp, const float* __restrict__ cr,
    unsigned short* __restrict__ PT2, float* __restrict__ out_zero)
{
    __shared__ float s_cp[32 * 97];
    __shared__ float s_cr[32 * 8];
    const int kt = blockIdx.x;       // 0..127
    const int tid = threadIdx.x;

    if (kt < 64) out_zero[(size_t)kt * 512 + tid] = 0.0f;   // 64*512 == 4096*8

    {   // coalesced stage of this kt's 32 rules
        const float4* cp4 = (const float4*)(cp + (size_t)kt * 32 * 96);
        for (int i = tid; i < 768; i += 512) {
            float4 v = cp4[i];
            int r = i / 24, c4 = i - r * 24;
            float* d = &s_cp[r * 97 + c4 * 4];
            d[0] = v.x; d[1] = v.y; d[2] = v.z; d[3] = v.w;
        }
        if (tid < 64) {
            float4 v = ((const float4*)(cr + (size_t)kt * 32 * 8))[tid];
            float* d = &s_cr[tid * 4];
            d[0] = v.x; d[1] = v.y; d[2] = v.z; d[3] = v.w;
        }
    }
    __syncthreads();

    const int g = tid >> 7, col = (tid >> 3) & 15, e = tid & 7;
    const int rr = g * 8 + e;
    #pragma unroll
    for (int j = 0; j < 8; ++j) {
        int n = j * 16 + col;
        float v = 0.f;
        if (n < 96) v = s_cp[rr * 97 + n];
        else if (n < 104) v = s_cr[rr * 8 + (n - 96)];
        PT2[(size_t)(kt * 8 + j) * 512 + tid] = f2bf(v);
    }
}

// ---------------- main: barrier-free K loop, direct L2->reg B fragments ----------------
// 8 waves = 4 colQuads x 2 kt-halves; each wave owns ALL 4 row-groups, so every
// B fragment is fetched exactly once per block via coalesced global_load_dwordx4
// from the XCD-resident PT2 strip. No LDS staging, no double buffer, no barriers
// between the table build and the epilogue. hv scales applied in f32 (AXPY).
__global__ __launch_bounds__(512, 4) void anfis_main10(
    const float* __restrict__ x,
    const float* __restrict__ center_base, const float* __restrict__ cdr,
    const float* __restrict__ wr,
    const unsigned short* __restrict__ PT2,
    float* __restrict__ out)
{
    __shared__ float s_params[48];
    __shared__ float s_x[64 * 12];
    __shared__ float s_low[64 * 36];
    __shared__ float s_highT[16 * 64];
    __shared__ __align__(16) float s_acc[64 * 116];   // 29,696 B

    const int tid = threadIdx.x;
    const int bid = blockIdx.x;
    const int ks = bid & 7;               // XCD id under round-robin dispatch
    const int mt = bid >> 3;
    const int b0 = mt * 64;
    const int kt0 = ks * 16;

    const int w = tid >> 6, l = tid & 63;

    // ---- phase 1: coalesced x load + params ----
    if (tid < 192) {
        float4 v = ((const float4*)(x + (size_t)b0 * NF))[tid];
        float* d = &s_x[tid * 4];
        d[0] = v.x; d[1] = v.y; d[2] = v.z; d[3] = v.w;
    }
    if (tid >= 500 && tid < 500 + NF) {
        int f = tid - 500;
        float c0 = center_base[f];
        float gap = softplus_f(cdr[f]) + 1e-3f;
        float w0 = softplus_f(wr[f * 2 + 0]) + 1e-3f;
        float w1 = softplus_f(wr[f * 2 + 1]) + 1e-3f;
        s_params[f * 4 + 0] = c0;
        s_params[f * 4 + 1] = c0 + gap;
        s_params[f * 4 + 2] = -0.5f / (w0 * w0);
        s_params[f * 4 + 3] = -0.5f / (w1 * w1);
    }
    __syncthreads();

    // ---- phase 2 (fused): per-thread memberships in registers -> low/high tables ----
    {
        const int row = tid >> 3, w8 = tid & 7;
        const float* xr = &s_x[row * 12];
        float m0a[NF], m1a[NF];
        float S = 1.f;
        #pragma unroll
        for (int f = 0; f < NF; ++f) {
            float4 pm = *(const float4*)&s_params[f * 4];
            float xv = xr[f];
            float d0 = xv - pm.x, d1 = xv - pm.y;
            float e0 = __expf(d0 * d0 * pm.z);
            float e1 = __expf(d1 * d1 * pm.w);
            m0a[f] = e0; m1a[f] = e1;
            S *= (e0 + e1);
        }
        float rc = 1.0f / (S + 1e-8f);
        #pragma unroll
        for (int i = 0; i < 4; ++i) {
            int ee = w8 * 4 + i;
            float p = 1.f;
            #pragma unroll
            for (int f = 0; f < 5; ++f)
                p *= ((ee >> f) & 1) ? m1a[f] : m0a[f];
            s_low[row * 36 + ee] = p;
        }
        #pragma unroll
        for (int i = 0; i < 2; ++i) {
            int t = w8 * 2 + i;
            int ktg = kt0 + t;
            float p = rc;
            #pragma unroll
            for (int ff = 0; ff < 7; ++ff)
                p *= ((ktg >> ff) & 1) ? m1a[5 + ff] : m0a[5 + ff];
            s_highT[t * 64 + row] = p;
        }
    }
    __syncthreads();      // tables stable for the rest of the kernel

    // ---- roles: 4 colQuads x 2 kt-halves; all 4 row-groups per wave ----
    const int h = w >> 2, cq = w & 3;
    const int col = l & 15, g = l >> 4;
    const int nj = (cq < 3) ? 2 : 1;
    const int jb = cq * 2;                // jsets {0,1},{2,3},{4,5},{6}

    // A-fragments for all 4 row-groups (built once; hv applied post-MFMA in f32)
    bf16x8 ah[4], al[4];
    #pragma unroll
    for (int i = 0; i < 4; ++i) {
        int rowA = i * 16 + col;
        f32x4v lo0 = *(const f32x4v*)&s_low[rowA * 36 + g * 8];
        f32x4v lo1 = *(const f32x4v*)&s_low[rowA * 36 + g * 8 + 4];
        build_split(lo0, lo1, ah[i], al[i]);
    }

    f32x4v acc[4][2];
    #pragma unroll
    for (int i = 0; i < 4; ++i)
        #pragma unroll
        for (int jj = 0; jj < 2; ++jj) acc[i][jj] = (f32x4v){0.f, 0.f, 0.f, 0.f};
    const f32x4v z4 = (f32x4v){0.f, 0.f, 0.f, 0.f};

    // my 8 k-tiles start at kt0 + h*8; plane (kt, j) = 1 KB, lane slice = l*16
    const unsigned char* pB = (const unsigned char*)PT2
                            + ((size_t)(kt0 + h * 8) << 13) + (size_t)l * 16;

    #pragma unroll
    for (int tt = 0; tt < 8; ++tt) {
        const int t = h * 8 + tt;
        // hv broadcasts for the 4 row-groups (lanes of a g-group read same 16B)
        f32x4v hv0 = *(const f32x4v*)&s_highT[t * 64 +  0 + g * 4];
        f32x4v hv1 = *(const f32x4v*)&s_highT[t * 64 + 16 + g * 4];
        f32x4v hv2 = *(const f32x4v*)&s_highT[t * 64 + 32 + g * 4];
        f32x4v hv3 = *(const f32x4v*)&s_highT[t * 64 + 48 + g * 4];
        #pragma unroll
        for (int jj = 0; jj < 2; ++jj) {
            if (jj < nj) {
                bf16x8 fr = *(const bf16x8*)(pB + tt * 8192 + (jb + jj) * 1024);
                f32x4v q0, q1, q2, q3;
                q0 = __builtin_amdgcn_mfma_f32_16x16x32_bf16(ah[0], fr, z4, 0, 0, 0);
                q1 = __builtin_amdgcn_mfma_f32_16x16x32_bf16(ah[1], fr, z4, 0, 0, 0);
                q2 = __builtin_amdgcn_mfma_f32_16x16x32_bf16(ah[2], fr, z4, 0, 0, 0);
                q3 = __builtin_amdgcn_mfma_f32_16x16x32_bf16(ah[3], fr, z4, 0, 0, 0);
                q0 = __builtin_amdgcn_mfma_f32_16x16x32_bf16(al[0], fr, q0, 0, 0, 0);
                q1 = __builtin_amdgcn_mfma_f32_16x16x32_bf16(al[1], fr, q1, 0, 0, 0);
                q2 = __builtin_amdgcn_mfma_f32_16x16x32_bf16(al[2], fr, q2, 0, 0, 0);
                q3 = __builtin_amdgcn_mfma_f32_16x16x32_bf16(al[3], fr, q3, 0, 0, 0);
                acc[0][jj] += hv0 * q0;
                acc[1][jj] += hv1 * q1;
                acc[2][jj] += hv2 * q2;
                acc[3][jj] += hv3 * q3;
            }
        }
    }

    // ---- epilogue: h0 stores, h1 accumulates, then x-weighted reduce + atomicAdd ----
    if (h == 0) {
        #pragma unroll
        for (int i = 0; i < 4; ++i)
            #pragma unroll
            for (int jj = 0; jj < 2; ++jj)
                if (jj < nj) {
                    int j = jb + jj;
                    #pragma unroll
                    for (int q = 0; q < 4; ++q)
                        s_acc[(i * 16 + g * 4 + q) * 116 + j * 16 + col] = acc[i][jj][q];
                }
    }
    __syncthreads();
    if (h == 1) {
        #pragma unroll
        for (int i = 0; i < 4; ++i)
            #pragma unroll
            for (int jj = 0; jj < 2; ++jj)
                if (jj < nj) {
                    int j = jb + jj;
                    #pragma unroll
                    for (int q = 0; q < 4; ++q)
                        s_acc[(i * 16 + g * 4 + q) * 116 + j * 16 + col] += acc[i][jj][q];
                }
    }
    __syncthreads();
    {
        const int row = tid >> 3, o = tid & 7;
        const float* ar = &s_acc[row * 116];
        float t = ar[96 + o];
        #pragma unroll
        for (int f = 0; f < NF; ++f) t = fmaf(s_x[row * 12 + f], ar[f * 8 + o], t);
        atomicAdd(&out[(size_t)(b0 + row) * NO + o], t);
    }
}

// ================= round-2 fallback path (proven; used only if ws too small) =================
__global__ __launch_bounds__(256) void anfis_prep(
    const float* __restrict__ cp, const float* __restrict__ cr,
    unsigned short* __restrict__ PT)
{
    const int n = blockIdx.x;
    const int t = threadIdx.x;
    if (n < 96) {
        #pragma unroll
        for (int i = 0; i < 16; ++i) { int r = i * 256 + t; PT[n * 4096 + r] = f2bf(cp[r * 96 + n]); }
    } else if (n < 104) {
        const int o = n - 96;
        #pragma unroll
        for (int i = 0; i < 16; ++i) { int r = i * 256 + t; PT[n * 4096 + r] = f2bf(cr[r * 8 + o]); }
    } else {
        #pragma unroll
        for (int i = 0; i < 16; ++i) PT[n * 4096 + i * 256 + t] = 0;
    }
}

__global__ __launch_bounds__(512) void anfis_mfma(
    const float* __restrict__ x,
    const float* __restrict__ center_base,
    const float* __restrict__ center_delta_raw,
    const float* __restrict__ width_raw,
    const unsigned short* __restrict__ PT,
    float* __restrict__ out)
{
    __shared__ float s_mem[16 * 26];
    __shared__ float s_low[16 * 36];
    __shared__ float s_high[16 * 132];
    __shared__ float s_red[8 * 16 * 113];

    const int tid = threadIdx.x;
    const int b0 = blockIdx.x * 16;

    if (tid < 16) {
        const int b = b0 + tid;
        float S = 1.0f;
        #pragma unroll
        for (int f = 0; f < NF; ++f) {
            float cb  = center_base[f];
            float gap = softplus_f(center_delta_raw[f]) + 1e-3f;
            float c0 = cb, c1 = cb + gap;
            float w0 = softplus_f(width_raw[f * 2 + 0]) + 1e-3f;
            float w1 = softplus_f(width_raw[f * 2 + 1]) + 1e-3f;
            float xv = x[b * NF + f];
            float d0 = xv - c0, d1 = xv - c1;
            float m0 = __expf(-d0 * d0 / (2.0f * w0 * w0));
            float m1 = __expf(-d1 * d1 / (2.0f * w1 * w1));
            s_mem[tid * 26 + f * 2 + 0] = m0;
            s_mem[tid * 26 + f * 2 + 1] = m1;
            S *= (m0 + m1);
        }
        s_mem[tid * 26 + 24] = 1.0f / (S + 1e-8f);
    }
    __syncthreads();
    if (tid < 256) {
        const int row = tid >> 4, w16 = tid & 15;
        const float* mrow = &s_mem[row * 26];
        #pragma unroll
        for (int e = 2 * w16; e <= 2 * w16 + 1; ++e) {
            float p = 1.0f;
            #pragma unroll
            for (int f = 0; f < 5; ++f) p *= mrow[f * 2 + ((e >> f) & 1)];
            s_low[row * 36 + e] = p;
        }
        float rcp = mrow[24];
        #pragma unroll
        for (int i = 0; i < 8; ++i) {
            int e = w16 + 16 * i;
            float p = rcp;
            #pragma unroll
            for (int ff = 0; ff < 7; ++ff) p *= mrow[(5 + ff) * 2 + ((e >> ff) & 1)];
            s_high[row * 132 + e] = p;
        }
    }
    __syncthreads();

    const int w = tid >> 6;
    const int l = tid & 63;
    const int col = l & 15;
    const int g   = l >> 4;

    f32x4v lo0 = *(const f32x4v*)&s_low[col * 36 + g * 8];
    f32x4v lo1 = *(const f32x4v*)&s_low[col * 36 + g * 8 + 4];
    f32x4v hq0 = *(const f32x4v*)&s_high[col * 132 + w * 16 + 0];
    f32x4v hq1 = *(const f32x4v*)&s_high[col * 132 + w * 16 + 4];
    f32x4v hq2 = *(const f32x4v*)&s_high[col * 132 + w * 16 + 8];
    f32x4v hq3 = *(const f32x4v*)&s_high[col * 132 + w * 16 + 12];

    const unsigned short* pB = PT + (size_t)col * 4096 + g * 8 + w * 512;

    f32x4v acc[7];
    #pragma unroll
    for (int j = 0; j < 7; ++j) acc[j] = (f32x4v){0.f, 0.f, 0.f, 0.f};

    bf16x8 bf[2][7];
    #pragma unroll
    for (int j = 0; j < 7; ++j) bf[0][j] = *(const bf16x8*)(pB + j * 65536 + 0 * 32);
    #pragma unroll
    for (int j = 0; j < 7; ++j) bf[1][j] = *(const bf16x8*)(pB + j * 65536 + 1 * 32);

    #pragma unroll
    for (int s = 0; s < 16; ++s) {
        const float hv = (s < 4) ? hq0[s & 3] : (s < 8) ? hq1[s & 3]
                        : (s < 12) ? hq2[s & 3] : hq3[s & 3];
        bf16x8 ah, al;
        #pragma unroll
        for (int e = 0; e < 8; ++e) {
            float v = ((e < 4) ? lo0[e & 3] : lo1[e & 3]) * hv;
            unsigned short h = f2bf(v);
            float vh = __uint_as_float(((unsigned)h) << 16);
            ah[e] = (short)h;
            al[e] = (short)f2bf(v - vh);
        }
        #pragma unroll
        for (int j = 0; j < 7; ++j) {
            acc[j] = __builtin_amdgcn_mfma_f32_16x16x32_bf16(ah, bf[s & 1][j], acc[j], 0, 0, 0);
            acc[j] = __builtin_amdgcn_mfma_f32_16x16x32_bf16(al, bf[s & 1][j], acc[j], 0, 0, 0);
        }
        if (s + 2 < 16) {
            #pragma unroll
            for (int j = 0; j < 7; ++j)
                bf[s & 1][j] = *(const bf16x8*)(pB + j * 65536 + (s + 2) * 32);
        }
    }

    #pragma unroll
    for (int j = 0; j < 7; ++j)
        #pragma unroll
        for (int q = 0; q < 4; ++q)
            s_red[(w * 16 + g * 4 + q) * 113 + j * 16 + col] = acc[j][q];
    __syncthreads();

    if (tid < 128) {
        const int row = tid >> 3, o = tid & 7;
        float xr[NF];
        #pragma unroll
        for (int f = 0; f < NF; ++f) xr[f] = x[(b0 + row) * NF + f];
        float outv = 0.0f;
        #pragma unroll
        for (int ww = 0; ww < 8; ++ww) {
            const float* ar = &s_red[(ww * 16 + row) * 113];
            float t2 = ar[96 + o];
            #pragma unroll
            for (int f = 0; f < NF; ++f) t2 = fmaf(xr[f], ar[f * 8 + o], t2);
            outv += t2;
        }
        out[(b0 + row) * NO + o] = outv;
    }
}

extern "C" void kernel_launch(void* const* d_in, const int* in_sizes, int n_in,
                              void* d_out, int out_size, void* d_ws, size_t ws_size,
                              hipStream_t stream) {
    const float* x   = (const float*)d_in[0];
    const float* cb  = (const float*)d_in[1];
    const float* cdr = (const float*)d_in[2];
    const float* wr  = (const float*)d_in[3];
    const float* cp  = (const float*)d_in[4];
    const float* cr  = (const float*)d_in[5];
    float* out = (float*)d_out;

    if (ws_size >= (size_t)WS_NEED) {
        unsigned short* PT2 = (unsigned short*)d_ws;
        anfis_prep4<<<128, 512, 0, stream>>>(cp, cr, PT2, out);
        anfis_main10<<<512, 512, 0, stream>>>(x, cb, cdr, wr, PT2, out);
    } else if (ws_size >= (size_t)PT_ELEMS * sizeof(unsigned short)) {
        unsigned short* PT = (unsigned short*)d_ws;
        anfis_prep<<<112, 256, 0, stream>>>(cp, cr, PT);
        anfis_mfma<<<NB / 16, 512, 0, stream>>>(x, cb, cdr, wr, PT, out);
    }
}

// Round 10
// 20.500 us; speedup vs baseline: 3.9880x; 3.9880x over previous
//
#include <hip/hip_runtime.h>
#include <math.h>

#define NF 12
#define NB 4096
#define NR 4096
#define NO 8

typedef float f32x4v __attribute__((ext_vector_type(4)));
typedef short bf16x8 __attribute__((ext_vector_type(8)));
typedef unsigned int uint32x4 __attribute__((ext_vector_type(4)));

// ---- ws layout ----
#define PT2_BYTES (128 * 8 * 512 * 2)      // 1,048,576 : bf16 [kt][j<8][512] fragment-ordered
#define PARAMS_OFF PT2_BYTES               // 48 f32
#define WS_NEED (PT2_BYTES + 2048)
// ---- r2 fallback ws layout ----
#define PT_ELEMS (112 * 4096)

__device__ __forceinline__ float softplus_f(float v) {
    return fmaxf(v, 0.0f) + log1pf(__expf(-fabsf(v)));
}
__device__ __forceinline__ unsigned short f2bf(float f) {
    unsigned u = __float_as_uint(f);
    u += 0x7FFFu + ((u >> 16) & 1u);
    return (unsigned short)(u >> 16);
}
__device__ __forceinline__ unsigned cvt_pk_bf16(float a, float b) {
    unsigned r;
    asm("v_cvt_pk_bf16_f32 %0, %1, %2" : "=v"(r) : "v"(a), "v"(b));
    return r;
}

// split an 8-vector of f32 into hi+lo bf16 fragments (error ~2^-18)
__device__ __forceinline__ void build_split(f32x4v va, f32x4v vb,
                                            bf16x8& ah, bf16x8& al) {
    unsigned h0 = cvt_pk_bf16(va[0], va[1]), h1 = cvt_pk_bf16(va[2], va[3]);
    unsigned h2 = cvt_pk_bf16(vb[0], vb[1]), h3 = cvt_pk_bf16(vb[2], vb[3]);
    f32x4v hia = { __uint_as_float(h0 << 16), __uint_as_float(h0 & 0xFFFF0000u),
                   __uint_as_float(h1 << 16), __uint_as_float(h1 & 0xFFFF0000u) };
    f32x4v hib = { __uint_as_float(h2 << 16), __uint_as_float(h2 & 0xFFFF0000u),
                   __uint_as_float(h3 << 16), __uint_as_float(h3 & 0xFFFF0000u) };
    f32x4v ea = va - hia;
    f32x4v eb = vb - hib;
    unsigned q0 = cvt_pk_bf16(ea[0], ea[1]), q1 = cvt_pk_bf16(ea[2], ea[3]);
    unsigned q2 = cvt_pk_bf16(eb[0], eb[1]), q3 = cvt_pk_bf16(eb[2], eb[3]);
    union { uint32x4 u; bf16x8 v; } A, B;
    A.u = (uint32x4){h0, h1, h2, h3};
    B.u = (uint32x4){q0, q1, q2, q3};
    ah = A.v; al = B.v;
}

// ---------------- prep: PT2 fragment-ordered + membership params + out zero ----------------
// (byte-identical to the proven R1 version)
__global__ __launch_bounds__(512) void anfis_prep2(
    const float* __restrict__ cp, const float* __restrict__ cr,
    const float* __restrict__ center_base, const float* __restrict__ cdr,
    const float* __restrict__ wr,
    unsigned short* __restrict__ PT2, float* __restrict__ params,
    float* __restrict__ out_zero)
{
    __shared__ float s_cp[32 * 97];
    __shared__ float s_cr[32 * 8];
    const int kt = blockIdx.x;       // 0..127
    const int tid = threadIdx.x;

    if (kt < 64) out_zero[(size_t)kt * 512 + tid] = 0.0f;   // 64*512 == 4096*8

    {   // coalesced stage of this kt's 32 rules
        const float4* cp4 = (const float4*)(cp + (size_t)kt * 32 * 96);
        for (int i = tid; i < 768; i += 512) {
            float4 v = cp4[i];
            int r = i / 24, c4 = i - r * 24;
            float* d = &s_cp[r * 97 + c4 * 4];
            d[0] = v.x; d[1] = v.y; d[2] = v.z; d[3] = v.w;
        }
        if (tid < 64) {
            float4 v = ((const float4*)(cr + (size_t)kt * 32 * 8))[tid];
            float* d = &s_cr[tid * 4];
            d[0] = v.x; d[1] = v.y; d[2] = v.z; d[3] = v.w;
        }
    }
    __syncthreads();

    const int g = tid >> 7, col = (tid >> 3) & 15, e = tid & 7;
    const int rr = g * 8 + e;
    #pragma unroll
    for (int j = 0; j < 8; ++j) {
        int n = j * 16 + col;
        float v = 0.f;
        if (n < 96) v = s_cp[rr * 97 + n];
        else if (n < 104) v = s_cr[rr * 8 + (n - 96)];
        PT2[(size_t)(kt * 8 + j) * 512 + tid] = f2bf(v);
    }

    if (kt == 0 && tid < NF) {
        float c0 = center_base[tid];
        float gap = softplus_f(cdr[tid]) + 1e-3f;
        float w0 = softplus_f(wr[tid * 2 + 0]) + 1e-3f;
        float w1 = softplus_f(wr[tid * 2 + 1]) + 1e-3f;
        params[tid * 4 + 0] = c0;
        params[tid * 4 + 1] = c0 + gap;
        params[tid * 4 + 2] = -0.5f / (w0 * w0);
        params[tid * 4 + 3] = -0.5f / (w1 * w1);
    }
}

// ---------------- main: BM=64; 8 waves = 2 rgPair x 4 colQuad ----------------
// AXPY scheme: A-frag = bf16split(low) built ONCE before the K loop; per kt the
// MFMA computes Q = (ah+al)*B from a zero C, then acc += hv_f32 * Q (pk_fma).
// This hoists the per-kt2 fragment build out of the loop and lets the wave split
// halve B-fragment LDS reads (each frag read once per rgPair, not per rg).
__global__ __launch_bounds__(512, 4) void anfis_main7(
    const float* __restrict__ x,
    const unsigned short* __restrict__ PT2,
    const float* __restrict__ params,
    float* __restrict__ out)
{
    __shared__ float s_params[48];
    __shared__ float s_mf[64 * 24];       // [row][f*2+m]
    __shared__ float s_prod[64 * 8];
    __shared__ float s_rcp[64];
    __shared__ float s_x[64 * 12];        // x rows (coalesced load, reused by epilogue)
    __shared__ float s_low[64 * 36];      // [row][32] features 0..4
    __shared__ float s_highT[16 * 64];    // [kt-local t][row]  (transposed for b128 hv read)
    __shared__ __align__(16) unsigned char s_B[2 * 16384];

    const int tid = threadIdx.x;
    const int bid = blockIdx.x;
    const int ks = bid & 7;               // XCD id under round-robin dispatch
    const int mt = bid >> 3;
    const int b0 = mt * 64;
    const int kt0 = ks * 16;

    const int w = tid >> 6, l = tid & 63;

    const unsigned char* ptBase = (const unsigned char*)PT2;
    // wave 7 stages only the never-read j=7 planes -> skip its loads entirely
    #define STAGE(c, buf) do {                                                        \
        if (w != 7) {                                                                 \
            const unsigned char* gb = ptBase + ((size_t)(kt0 + 2 * (c)) << 13);       \
            unsigned char* lb = &s_B[(buf) * 16384];                                  \
            __builtin_amdgcn_global_load_lds(                                         \
                (const __attribute__((address_space(1))) void*)(gb + w * 1024 + l * 16),  \
                (__attribute__((address_space(3))) void*)(lb + w * 1024), 16, 0, 0);  \
            __builtin_amdgcn_global_load_lds(                                         \
                (const __attribute__((address_space(1))) void*)(gb + (8 + w) * 1024 + l * 16), \
                (__attribute__((address_space(3))) void*)(lb + (8 + w) * 1024), 16, 0, 0);\
        }                                                                             \
    } while (0)

    // prefetch chunks 0 and 1 immediately: latency hides under the whole preamble
    STAGE(0, 0);
    STAGE(1, 1);

    // ---- phase A: params + coalesced x load ----
    if (tid < 192) {
        float4 v = ((const float4*)(x + (size_t)b0 * NF))[tid];
        float* d = &s_x[tid * 4];
        d[0] = v.x; d[1] = v.y; d[2] = v.z; d[3] = v.w;
    }
    if (tid >= 500) {
        int f = tid - 500;
        ((float4*)s_params)[f] = ((const float4*)params)[f];
    }
    __syncthreads();

    // ---- memberships (64 rows x 6 feature-pairs) ----
    if (tid < 384) {
        int row = tid / 6, fp = tid - row * 6;
        float pr = 1.f;
        #pragma unroll
        for (int h = 0; h < 2; ++h) {
            int f = fp + h * 6;
            float xv = s_x[row * 12 + f];
            float4 pm = *(const float4*)&s_params[f * 4];
            float d0 = xv - pm.x, d1 = xv - pm.y;
            float m0 = __expf(d0 * d0 * pm.z);
            float m1 = __expf(d1 * d1 * pm.w);
            s_mf[row * 24 + f * 2 + 0] = m0;
            s_mf[row * 24 + f * 2 + 1] = m1;
            pr *= (m0 + m1);
        }
        s_prod[row * 8 + fp] = pr;
    }
    __syncthreads();
    if (tid < 64) {
        float S = 1.f;
        #pragma unroll
        for (int i = 0; i < 6; ++i) S *= s_prod[tid * 8 + i];
        s_rcp[tid] = 1.0f / (S + 1e-8f);
    }
    __syncthreads();

    // ---- low[32] and highT[16][64] tables ----
    {
        int row = tid >> 3, w8 = tid & 7;
        const float* mr = &s_mf[row * 24];
        #pragma unroll
        for (int i = 0; i < 4; ++i) {
            int ee = w8 * 4 + i;
            float p = 1.f;
            #pragma unroll
            for (int f = 0; f < 5; ++f) p *= mr[f * 2 + ((ee >> f) & 1)];
            s_low[row * 36 + ee] = p;
        }
        float rc = s_rcp[row];
        #pragma unroll
        for (int i = 0; i < 2; ++i) {
            int t = w8 * 2 + i;
            int ktg = kt0 + t;
            float p = rc;
            #pragma unroll
            for (int ff = 0; ff < 7; ++ff) p *= mr[(5 + ff) * 2 + ((ktg >> ff) & 1)];
            s_highT[t * 64 + row] = p;
        }
    }
    __syncthreads();      // tables visible; vmcnt drained -> buf0, buf1 ready

    // ---- K loop: 8 chunks of 64 rules ----
    const int rp = w >> 2, cq = w & 3;    // rgPair, colQuad
    const int col = l & 15, g = l >> 4;
    const int nj = (cq < 3) ? 2 : 1;
    const int jb = cq * 2;                // jsets {0,1},{2,3},{4,5},{6}

    // A-fragments built ONCE (hv applied post-MFMA in f32)
    bf16x8 ah[2], al[2];
    #pragma unroll
    for (int i = 0; i < 2; ++i) {
        int rowA = (rp * 2 + i) * 16 + col;
        f32x4v lo0 = *(const f32x4v*)&s_low[rowA * 36 + g * 8];
        f32x4v lo1 = *(const f32x4v*)&s_low[rowA * 36 + g * 8 + 4];
        build_split(lo0, lo1, ah[i], al[i]);
    }

    f32x4v acc[2][2];
    #pragma unroll
    for (int i = 0; i < 2; ++i)
        #pragma unroll
        for (int jj = 0; jj < 2; ++jj) acc[i][jj] = (f32x4v){0.f, 0.f, 0.f, 0.f};
    const f32x4v z4 = (f32x4v){0.f, 0.f, 0.f, 0.f};

    const int hoff0 = (rp * 2 + 0) * 16 + g * 4;
    const int hoff1 = (rp * 2 + 1) * 16 + g * 4;

    #pragma unroll 1
    for (int c = 0; c < 8; ++c) {
        const int cur = c & 1;
        if (c >= 1 && c + 1 < 8) STAGE(c + 1, cur ^ 1);
        #pragma unroll
        for (int kt2 = 0; kt2 < 2; ++kt2) {
            const int t = c * 2 + kt2;
            const unsigned char* base = &s_B[cur * 16384 + kt2 * 8192 + l * 16];
            bf16x8 fr0 = *(const bf16x8*)(base + jb * 1024);
            f32x4v hv0 = *(const f32x4v*)&s_highT[t * 64 + hoff0];
            f32x4v hv1 = *(const f32x4v*)&s_highT[t * 64 + hoff1];
            f32x4v q00, q10;
            q00 = __builtin_amdgcn_mfma_f32_16x16x32_bf16(ah[0], fr0, z4, 0, 0, 0);
            q00 = __builtin_amdgcn_mfma_f32_16x16x32_bf16(al[0], fr0, q00, 0, 0, 0);
            q10 = __builtin_amdgcn_mfma_f32_16x16x32_bf16(ah[1], fr0, z4, 0, 0, 0);
            q10 = __builtin_amdgcn_mfma_f32_16x16x32_bf16(al[1], fr0, q10, 0, 0, 0);
            acc[0][0] += hv0 * q00;
            acc[1][0] += hv1 * q10;
            if (nj == 2) {
                bf16x8 fr1 = *(const bf16x8*)(base + (jb + 1) * 1024);
                f32x4v q01, q11;
                q01 = __builtin_amdgcn_mfma_f32_16x16x32_bf16(ah[0], fr1, z4, 0, 0, 0);
                q01 = __builtin_amdgcn_mfma_f32_16x16x32_bf16(al[0], fr1, q01, 0, 0, 0);
                q11 = __builtin_amdgcn_mfma_f32_16x16x32_bf16(ah[1], fr1, z4, 0, 0, 0);
                q11 = __builtin_amdgcn_mfma_f32_16x16x32_bf16(al[1], fr1, q11, 0, 0, 0);
                acc[0][1] += hv0 * q01;
                acc[1][1] += hv1 * q11;
            }
        }
        __syncthreads();
    }
    #undef STAGE

    // ---- fused epilogue: acc -> LDS (overlay dead s_B) -> x-weighted reduce -> atomicAdd ----
    float* s_acc = (float*)s_B;           // 64*116*4 = 29,696 B
    #pragma unroll
    for (int i = 0; i < 2; ++i) {
        #pragma unroll
        for (int jj = 0; jj < 2; ++jj) {
            if (jj < nj) {
                int j = jb + jj;
                #pragma unroll
                for (int q = 0; q < 4; ++q)
                    s_acc[((rp * 2 + i) * 16 + g * 4 + q) * 116 + j * 16 + col] = acc[i][jj][q];
            }
        }
    }
    __syncthreads();
    {
        const int row = tid >> 3, o = tid & 7;
        const float* ar = &s_acc[row * 116];
        float t = ar[96 + o];
        #pragma unroll
        for (int f = 0; f < NF; ++f) t = fmaf(s_x[row * 12 + f], ar[f * 8 + o], t);
        atomicAdd(&out[(size_t)(b0 + row) * NO + o], t);
    }
}

// ================= round-2 fallback path (proven; used only if ws too small) =================
__global__ __launch_bounds__(256) void anfis_prep(
    const float* __restrict__ cp, const float* __restrict__ cr,
    unsigned short* __restrict__ PT)
{
    const int n = blockIdx.x;
    const int t = threadIdx.x;
    if (n < 96) {
        #pragma unroll
        for (int i = 0; i < 16; ++i) { int r = i * 256 + t; PT[n * 4096 + r] = f2bf(cp[r * 96 + n]); }
    } else if (n < 104) {
        const int o = n - 96;
        #pragma unroll
        for (int i = 0; i < 16; ++i) { int r = i * 256 + t; PT[n * 4096 + r] = f2bf(cr[r * 8 + o]); }
    } else {
        #pragma unroll
        for (int i = 0; i < 16; ++i) PT[n * 4096 + i * 256 + t] = 0;
    }
}

__global__ __launch_bounds__(512) void anfis_mfma(
    const float* __restrict__ x,
    const float* __restrict__ center_base,
    const float* __restrict__ center_delta_raw,
    const float* __restrict__ width_raw,
    const unsigned short* __restrict__ PT,
    float* __restrict__ out)
{
    __shared__ float s_mem[16 * 26];
    __shared__ float s_low[16 * 36];
    __shared__ float s_high[16 * 132];
    __shared__ float s_red[8 * 16 * 113];

    const int tid = threadIdx.x;
    const int b0 = blockIdx.x * 16;

    if (tid < 16) {
        const int b = b0 + tid;
        float S = 1.0f;
        #pragma unroll
        for (int f = 0; f < NF; ++f) {
            float cb  = center_base[f];
            float gap = softplus_f(center_delta_raw[f]) + 1e-3f;
            float c0 = cb, c1 = cb + gap;
            float w0 = softplus_f(width_raw[f * 2 + 0]) + 1e-3f;
            float w1 = softplus_f(width_raw[f * 2 + 1]) + 1e-3f;
            float xv = x[b * NF + f];
            float d0 = xv - c0, d1 = xv - c1;
            float m0 = __expf(-d0 * d0 / (2.0f * w0 * w0));
            float m1 = __expf(-d1 * d1 / (2.0f * w1 * w1));
            s_mem[tid * 26 + f * 2 + 0] = m0;
            s_mem[tid * 26 + f * 2 + 1] = m1;
            S *= (m0 + m1);
        }
        s_mem[tid * 26 + 24] = 1.0f / (S + 1e-8f);
    }
    __syncthreads();
    if (tid < 256) {
        const int row = tid >> 4, w16 = tid & 15;
        const float* mrow = &s_mem[row * 26];
        #pragma unroll
        for (int e = 2 * w16; e <= 2 * w16 + 1; ++e) {
            float p = 1.0f;
            #pragma unroll
            for (int f = 0; f < 5; ++f) p *= mrow[f * 2 + ((e >> f) & 1)];
            s_low[row * 36 + e] = p;
        }
        float rcp = mrow[24];
        #pragma unroll
        for (int i = 0; i < 8; ++i) {
            int e = w16 + 16 * i;
            float p = rcp;
            #pragma unroll
            for (int ff = 0; ff < 7; ++ff) p *= mrow[(5 + ff) * 2 + ((e >> ff) & 1)];
            s_high[row * 132 + e] = p;
        }
    }
    __syncthreads();

    const int w = tid >> 6;
    const int l = tid & 63;
    const int col = l & 15;
    const int g   = l >> 4;

    f32x4v lo0 = *(const f32x4v*)&s_low[col * 36 + g * 8];
    f32x4v lo1 = *(const f32x4v*)&s_low[col * 36 + g * 8 + 4];
    f32x4v hq0 = *(const f32x4v*)&s_high[col * 132 + w * 16 + 0];
    f32x4v hq1 = *(const f32x4v*)&s_high[col * 132 + w * 16 + 4];
    f32x4v hq2 = *(const f32x4v*)&s_high[col * 132 + w * 16 + 8];
    f32x4v hq3 = *(const f32x4v*)&s_high[col * 132 + w * 16 + 12];

    const unsigned short* pB = PT + (size_t)col * 4096 + g * 8 + w * 512;

    f32x4v acc[7];
    #pragma unroll
    for (int j = 0; j < 7; ++j) acc[j] = (f32x4v){0.f, 0.f, 0.f, 0.f};

    bf16x8 bf[2][7];
    #pragma unroll
    for (int j = 0; j < 7; ++j) bf[0][j] = *(const bf16x8*)(pB + j * 65536 + 0 * 32);
    #pragma unroll
    for (int j = 0; j < 7; ++j) bf[1][j] = *(const bf16x8*)(pB + j * 65536 + 1 * 32);

    #pragma unroll
    for (int s = 0; s < 16; ++s) {
        const float hv = (s < 4) ? hq0[s & 3] : (s < 8) ? hq1[s & 3]
                        : (s < 12) ? hq2[s & 3] : hq3[s & 3];
        bf16x8 ah, al;
        #pragma unroll
        for (int e = 0; e < 8; ++e) {
            float v = ((e < 4) ? lo0[e & 3] : lo1[e & 3]) * hv;
            unsigned short h = f2bf(v);
            float vh = __uint_as_float(((unsigned)h) << 16);
            ah[e] = (short)h;
            al[e] = (short)f2bf(v - vh);
        }
        #pragma unroll
        for (int j = 0; j < 7; ++j) {
            acc[j] = __builtin_amdgcn_mfma_f32_16x16x32_bf16(ah, bf[s & 1][j], acc[j], 0, 0, 0);
            acc[j] = __builtin_amdgcn_mfma_f32_16x16x32_bf16(al, bf[s & 1][j], acc[j], 0, 0, 0);
        }
        if (s + 2 < 16) {
            #pragma unroll
            for (int j = 0; j < 7; ++j)
                bf[s & 1][j] = *(const bf16x8*)(pB + j * 65536 + (s + 2) * 32);
        }
    }

    #pragma unroll
    for (int j = 0; j < 7; ++j)
        #pragma unroll
        for (int q = 0; q < 4; ++q)
            s_red[(w * 16 + g * 4 + q) * 113 + j * 16 + col] = acc[j][q];
    __syncthreads();

    if (tid < 128) {
        const int row = tid >> 3, o = tid & 7;
        float xr[NF];
        #pragma unroll
        for (int f = 0; f < NF; ++f) xr[f] = x[(b0 + row) * NF + f];
        float outv = 0.0f;
        #pragma unroll
        for (int ww = 0; ww < 8; ++ww) {
            const float* ar = &s_red[(ww * 16 + row) * 113];
            float t2 = ar[96 + o];
            #pragma unroll
            for (int f = 0; f < NF; ++f) t2 = fmaf(xr[f], ar[f * 8 + o], t2);
            outv += t2;
        }
        out[(b0 + row) * NO + o] = outv;
    }
}

extern "C" void kernel_launch(void* const* d_in, const int* in_sizes, int n_in,
                              void* d_out, int out_size, void* d_ws, size_t ws_size,
                              hipStream_t stream) {
    const float* x   = (const float*)d_in[0];
    const float* cb  = (const float*)d_in[1];
    const float* cdr = (const float*)d_in[2];
    const float* wr  = (const float*)d_in[3];
    const float* cp  = (const float*)d_in[4];
    const float* cr  = (const float*)d_in[5];
    float* out = (float*)d_out;

    if (ws_size >= (size_t)WS_NEED) {
        unsigned short* PT2 = (unsigned short*)d_ws;
        float* params = (float*)((char*)d_ws + PARAMS_OFF);
        anfis_prep2<<<128, 512, 0, stream>>>(cp, cr, cb, cdr, wr, PT2, params, out);
        anfis_main7<<<512, 512, 0, stream>>>(x, PT2, params, out);
    } else if (ws_size >= (size_t)PT_ELEMS * sizeof(unsigned short)) {
        unsigned short* PT = (unsigned short*)d_ws;
        anfis_prep<<<112, 256, 0, stream>>>(cp, cr, PT);
        anfis_mfma<<<NB / 16, 512, 0, stream>>>(x, cb, cdr, wr, PT, out);
    }
}